// Round 11
// baseline (415.534 us; speedup 1.0000x reference)
//
#include <hip/hip_runtime.h>
#include <hip/hip_bf16.h>
#include <cstddef>

#define MIN_VALUE_F (-3.402823466e38f)

// B=4, C=64, T=256, D=256, H=4, DK=64, OUT=256, M = B*C*T = 65536

typedef __attribute__((ext_vector_type(8))) __bf16 bfrag;    // MFMA A/B operand (4 VGPR)
typedef __attribute__((ext_vector_type(4))) float f32x4;     // MFMA C/D operand

__device__ __forceinline__ float bf2f(unsigned int u) {
    union { unsigned int i; float f; } v; v.i = u << 16; return v.f;
}
__device__ __forceinline__ unsigned short f2bf(float f) {
    union { float f; unsigned int i; } v; v.f = f;
    return (unsigned short)((v.i + 0x7fffu + ((v.i >> 16) & 1u)) >> 16);
}
__device__ __forceinline__ unsigned int cvt2(float a, float b) {
    __hip_bfloat16 lo = __float2bfloat16(a);
    __hip_bfloat16 hi = __float2bfloat16(b);
    union { __hip_bfloat16 h[2]; unsigned int u; } x;
    x.h[0] = lo; x.h[1] = hi;
    return x.u;
}
__device__ __forceinline__ bfrag negf(bfrag v) {
    union { bfrag b; unsigned int u[4]; } x; x.b = v;
    #pragma unroll
    for (int i = 0; i < 4; ++i) x.u[i] ^= 0x80008000u;
    return x.b;
}

typedef __attribute__((address_space(3))) void lds_void_t;
typedef const __attribute__((address_space(1))) void gmem_void_t;
__device__ __forceinline__ void glds16(const void* g, void* l) {
    __builtin_amdgcn_global_load_lds((gmem_void_t*)g, (lds_void_t*)l, 16, 0, 0);
}

// fragment read from XOR-swizzled row-major 64x64 bf16 tile (row stride 64 ushorts) [attn]
__device__ __forceinline__ bfrag rdfrag(const unsigned short* arr, int row, int slot) {
    const int s = slot ^ (row & 7);
    return *(const bfrag*)&arr[row * 64 + s * 8];
}

// ---------------- Weight prepass: f32 (K=256,N=256) -> bf16 fragment-ordered images ----
// Per weight pair emits THREE images (r, i, -i), each 65536 ush:
// [nt(4)][s(8)][n(64)][k(32)], value = w[(s*32+k)*256 + nt*64+n]. Waves read MFMA
// B-fragments DIRECTLY from these (L2-hot), no LDS round-trip, no runtime negation.
__global__ __launch_bounds__(256)
void wprep_kernel(const float* __restrict__ wr, const float* __restrict__ wi,
                  unsigned short* __restrict__ dst)
{
    const int which = blockIdx.y;              // 0=r, 1=i, 2=-i
    const float* w = (which == 0) ? wr : wi;
    const float sgn = (which == 2) ? -1.f : 1.f;
    const int cid = blockIdx.x * 256 + threadIdx.x;   // 0..8191 chunks (16B each)
    const int u0 = cid * 8;
    const int k  = u0 & 31;
    const int n  = (u0 >> 5) & 63;
    const int s  = (u0 >> 11) & 7;
    const int nt = u0 >> 14;
    const int col = nt * 64 + n;
    const int kb = s * 32 + k;
    unsigned int p[4];
    #pragma unroll
    for (int jj = 0; jj < 4; ++jj) {
        const float a = sgn * w[(size_t)(kb + 2 * jj) * 256 + col];
        const float b = sgn * w[(size_t)(kb + 2 * jj + 1) * 256 + col];
        p[jj] = cvt2(a, b);
    }
    uint4 q; q.x = p[0]; q.y = p[1]; q.z = p[2]; q.w = p[3];
    *(uint4*)&dst[(size_t)which * 65536 + u0] = q;
}

// ---------------- Stage 1: complex QKV projection via MFMA ----------------
// 64x64 tile, BK=32, 8 K-steps, 4 waves, A-only LDS dbuf (2x8KB), XCD-chunked grid.
// W fragments read DIRECT from L2-hot images (r/i/-i) -> per step only 6 LDS ops,
// no negf, no W staging. 16 KB LDS + <=102 VGPR -> 5+ blocks/CU for TLP.
#define P_LOADA(s) { \
    const size_t o_ = (size_t)(m0 + arow) * 256 + (s) * 32 + apos * 8; \
    fr0 = *(const float4*)(xr + o_); \
    fr1 = *(const float4*)(xr + o_ + 4); \
    fi0 = *(const float4*)(xi + o_); \
    fi1 = *(const float4*)(xi + o_ + 4); }

#define P_WRITE(buf) { \
    unsigned short* B_ = SH + (buf) * 4096; \
    uint4 p_, q_; \
    p_.x = cvt2(fr0.x, fr0.y); p_.y = cvt2(fr0.z, fr0.w); \
    p_.z = cvt2(fr1.x, fr1.y); p_.w = cvt2(fr1.z, fr1.w); \
    q_.x = cvt2(fi0.x, fi0.y); q_.y = cvt2(fi0.z, fi0.w); \
    q_.z = cvt2(fi1.x, fi1.y); q_.w = cvt2(fi1.z, fi1.w); \
    *(uint4*)&B_[aidx] = p_; \
    *(uint4*)&B_[2048 + aidx] = q_; }

__global__ __launch_bounds__(256, 5)
void proj_mfma(const float* __restrict__ xq_r, const float* __restrict__ xq_i,
               const float* __restrict__ xk_r, const float* __restrict__ xk_i,
               const float* __restrict__ xv_r, const float* __restrict__ xv_i,
               const unsigned short* __restrict__ wimg,
               const float* __restrict__ bq_r, const float* __restrict__ bq_i,
               const float* __restrict__ bk_r, const float* __restrict__ bk_i,
               const float* __restrict__ bv_r, const float* __restrict__ bv_i,
               unsigned short* __restrict__ ws_out)
{
    __shared__ __align__(16) unsigned short SH[8192];   // 16 KB: 2 bufs x (Ar|Ai)

    // XCD-chunked bijective swizzle: 12288 blocks = 8 XCDs x 1536
    const int bid = blockIdx.x;
    const int work = (bid & 7) * 1536 + (bid >> 3);
    const int ny = work & 3;                 // n-tile (head), innermost -> same XCD
    const int rest = work >> 2;              // 0..3071
    const int m0 = (rest & 1023) * 64;
    const int pz = rest >> 10;

    const float *xr, *xi, *br_, *bi_;
    if (pz == 0)      { xr = xq_r; xi = xq_i; br_ = bq_r; bi_ = bq_i; }
    else if (pz == 1) { xr = xk_r; xi = xk_i; br_ = bk_r; bi_ = bk_i; }
    else              { xr = xv_r; xi = xv_i; br_ = bv_r; bi_ = bv_i; }
    unsigned short* outr = ws_out + (size_t)pz * 2 * 16777216;
    unsigned short* outi = outr + 16777216;

    const int tid = threadIdx.x;
    const int lane = tid & 63, wv = tid >> 6;
    const int l15 = lane & 15, hi = lane >> 4;
    const int wm = (wv >> 1) * 32, wn = (wv & 1) * 32;

    const unsigned short* wb = wimg + (size_t)pz * 196608 + ny * 16384;
    const unsigned short* wr_img = wb;              // [s(8)][n(64)][k(32)]
    const unsigned short* wi_img = wb + 65536;
    const unsigned short* wn_img = wb + 131072;     // pre-negated wi

    const int arow = tid >> 2;
    const int apos = tid & 3;
    const int aidx = arow * 32 + ((apos ^ ((arow >> 1) & 3)) << 3);
    float4 fr0, fr1, fi0, fi1;

    // per-lane B-fragment offsets within an image (n*32 + k)
    const int fb0 = (wn + l15) * 32 + hi * 8;
    const int fb1 = (wn + 16 + l15) * 32 + hi * 8;

    f32x4 accR[2][2] = {}, accI[2][2] = {};

    P_LOADA(0);
    P_WRITE(0);
    __syncthreads();

    #pragma unroll
    for (int s = 0; s < 8; ++s) {
        // W fragments (L2-hot), issued BEFORE the A prefetch -> MFMA waits vmcnt(4)
        const bfrag br0 = *(const bfrag*)&wr_img[s * 2048 + fb0];
        const bfrag br1 = *(const bfrag*)&wr_img[s * 2048 + fb1];
        const bfrag bi0 = *(const bfrag*)&wi_img[s * 2048 + fb0];
        const bfrag bi1 = *(const bfrag*)&wi_img[s * 2048 + fb1];
        const bfrag nb0 = *(const bfrag*)&wn_img[s * 2048 + fb0];
        const bfrag nb1 = *(const bfrag*)&wn_img[s * 2048 + fb1];
        if (s < 7) P_LOADA(s + 1);
        const unsigned short* As_r = SH + (s & 1) * 4096;
        const unsigned short* As_i = As_r + 2048;
        bfrag ar[2], ai[2];
        #pragma unroll
        for (int mf = 0; mf < 2; ++mf) {
            const int m = wm + mf * 16 + l15;
            const int idx = m * 32 + ((hi ^ ((m >> 1) & 3)) << 3);
            ar[mf] = *(const bfrag*)&As_r[idx];
            ai[mf] = *(const bfrag*)&As_i[idx];
        }
        #pragma unroll
        for (int mf = 0; mf < 2; ++mf) {
            accR[mf][0] = __builtin_amdgcn_mfma_f32_16x16x32_bf16(ar[mf], br0, accR[mf][0], 0, 0, 0);
            accR[mf][0] = __builtin_amdgcn_mfma_f32_16x16x32_bf16(ai[mf], nb0, accR[mf][0], 0, 0, 0);
            accI[mf][0] = __builtin_amdgcn_mfma_f32_16x16x32_bf16(ai[mf], br0, accI[mf][0], 0, 0, 0);
            accI[mf][0] = __builtin_amdgcn_mfma_f32_16x16x32_bf16(ar[mf], bi0, accI[mf][0], 0, 0, 0);
            accR[mf][1] = __builtin_amdgcn_mfma_f32_16x16x32_bf16(ar[mf], br1, accR[mf][1], 0, 0, 0);
            accR[mf][1] = __builtin_amdgcn_mfma_f32_16x16x32_bf16(ai[mf], nb1, accR[mf][1], 0, 0, 0);
            accI[mf][1] = __builtin_amdgcn_mfma_f32_16x16x32_bf16(ai[mf], br1, accI[mf][1], 0, 0, 0);
            accI[mf][1] = __builtin_amdgcn_mfma_f32_16x16x32_bf16(ar[mf], bi1, accI[mf][1], 0, 0, 0);
        }
        if (s < 7) P_WRITE((s + 1) & 1);
        __syncthreads();
    }

    // ---- epilogue: bias, stage 64x64 bf16 tile (r @0, i @4096), coalesced store
    const int bc = m0 >> 8, b = bc >> 6, c = bc & 63, t0 = m0 & 255;
    #pragma unroll
    for (int nf = 0; nf < 2; ++nf) {
        const int n_loc = wn + nf * 16 + l15;
        const int n_glob = ny * 64 + n_loc;
        const float vbr = br_[n_glob], vbi = bi_[n_glob];
        const float addR = vbr - vbi, addI = vbr + vbi;
        #pragma unroll
        for (int mf = 0; mf < 2; ++mf) {
            #pragma unroll
            for (int r = 0; r < 4; ++r) {
                const int m_loc = wm + mf * 16 + hi * 4 + r;
                SH[m_loc * 64 + n_loc] = f2bf(accR[mf][nf][r] + addR);
                SH[4096 + m_loc * 64 + n_loc] = f2bf(accI[mf][nf][r] + addI);
            }
        }
    }
    __syncthreads();
    const int h = ny;
    #pragma unroll
    for (int p = 0; p < 2; ++p) {
        const int tr = (tid >> 3) + p * 32;
        const int dk = (tid & 7) * 8;
        const int L = tr * 64 + dk;
        const size_t g = (((size_t)(b * 4 + h) * 256 + (t0 + tr)) * 64 + c) * 64 + dk;
        *(uint4*)&outr[g] = *(const uint4*)&SH[L];
        *(uint4*)&outi[g] = *(const uint4*)&SH[4096 + L];
    }
}

// ---------------- Stage 2: fused complex attention per (b,h,t), MFMA (unchanged) ------
__global__ __launch_bounds__(256)
void attn_mfma(const unsigned short* __restrict__ Qg_r, const unsigned short* __restrict__ Qg_i,
               const unsigned short* __restrict__ Kg_r, const unsigned short* __restrict__ Kg_i,
               const unsigned short* __restrict__ Vg_r, const unsigned short* __restrict__ Vg_i,
               const int* __restrict__ mask,
               unsigned short* __restrict__ Xr, unsigned short* __restrict__ Xi)
{
    __shared__ __align__(16) unsigned short sQr[4096], sQi[4096];   // Q, then P
    __shared__ __align__(16) unsigned short sKr[4096], sKi[4096];
    __shared__ __align__(16) unsigned short sVr[4608], sVi[4608];   // V^T, rows padded to 72
    __shared__ int smask[64];

    const int bht = blockIdx.x;
    const int b = bht >> 10;
    const int h = (bht >> 8) & 3;
    const int t = bht & 255;
    const size_t base = (size_t)bht * 4096;
    const int tid = threadIdx.x;
    const int lane = tid & 63, wv = tid >> 6;
    const int l15 = lane & 15, hi = lane >> 4;

    const int ep = (lane & 31) * 2;
    const int dch = wv * 2 + (lane >> 5);
    const unsigned short* vr0p = Vg_r + base + (size_t)ep * 64 + dch * 8;
    const unsigned short* vi0p = Vg_i + base + (size_t)ep * 64 + dch * 8;
    const uint4 vr0 = *(const uint4*)vr0p;
    const uint4 vr1 = *(const uint4*)(vr0p + 64);
    const uint4 vi0 = *(const uint4*)vi0p;
    const uint4 vi1 = *(const uint4*)(vi0p + 64);

    #pragma unroll
    for (int i = 0; i < 2; ++i) {
        const int ch = wv * 128 + i * 64 + lane;
        const int r = ch >> 3, cg = ch & 7;
        const int so = r * 64 + ((cg ^ (r & 7)) << 3);
        const int dofs = (wv * 128 + i * 64) << 3;
        glds16(Qg_r + base + so, &sQr[dofs]);
        glds16(Qg_i + base + so, &sQi[dofs]);
        glds16(Kg_r + base + so, &sKr[dofs]);
        glds16(Kg_i + base + so, &sKi[dofs]);
    }
    if (tid < 64) smask[tid] = mask[b * 64 + tid];

    {
        union { uint4 v; unsigned short s[8]; } ar0, ar1, ai0, ai1;
        ar0.v = vr0; ar1.v = vr1; ai0.v = vi0; ai1.v = vi1;
        #pragma unroll
        for (int j = 0; j < 8; ++j) {
            const int d = dch * 8 + j;
            *(unsigned int*)&sVr[d * 72 + ep] = (unsigned)ar0.s[j] | ((unsigned)ar1.s[j] << 16);
            *(unsigned int*)&sVi[d * 72 + ep] = (unsigned)ai0.s[j] | ((unsigned)ai1.s[j] << 16);
        }
    }
    __syncthreads();

    const int cq = wv * 16 + l15;
    f32x4 aR[4] = {}, aI[4] = {};
    #pragma unroll
    for (int ks = 0; ks < 2; ++ks) {
        const int slot = ks * 4 + hi;
        const bfrag qr = rdfrag(sQr, cq, slot);
        const bfrag qi = rdfrag(sQi, cq, slot);
        const bfrag nqi = negf(qi);
        #pragma unroll
        for (int et = 0; et < 4; ++et) {
            const int re = et * 16 + l15;
            const bfrag kr = rdfrag(sKr, re, slot);
            const bfrag ki = rdfrag(sKi, re, slot);
            aR[et] = __builtin_amdgcn_mfma_f32_16x16x32_bf16(kr, qr, aR[et], 0, 0, 0);
            aR[et] = __builtin_amdgcn_mfma_f32_16x16x32_bf16(ki, qi, aR[et], 0, 0, 0);
            aI[et] = __builtin_amdgcn_mfma_f32_16x16x32_bf16(ki, qr, aI[et], 0, 0, 0);
            aI[et] = __builtin_amdgcn_mfma_f32_16x16x32_bf16(kr, nqi, aI[et], 0, 0, 0);
        }
    }
    __syncthreads();

    const float scale = 0.125f;
    float amp[4][4], ex[4][4];
    float mx = MIN_VALUE_F;
    #pragma unroll
    for (int et = 0; et < 4; ++et) {
        #pragma unroll
        for (int r = 0; r < 4; ++r) {
            const float sr = aR[et][r] * scale;
            const float si = aI[et][r] * scale;
            float a = sqrtf(fmaf(sr, sr, si * si));
            if (smask[et * 16 + hi * 4 + r] == 0) a = MIN_VALUE_F;
            amp[et][r] = a;
            mx = fmaxf(mx, a);
        }
    }
    mx = fmaxf(mx, __shfl_xor(mx, 16, 64));
    mx = fmaxf(mx, __shfl_xor(mx, 32, 64));
    float sm = 0.f;
    #pragma unroll
    for (int et = 0; et < 4; ++et) {
        #pragma unroll
        for (int r = 0; r < 4; ++r) {
            const float e_ = expf(amp[et][r] - mx);
            ex[et][r] = e_; sm += e_;
        }
    }
    sm += __shfl_xor(sm, 16, 64);
    sm += __shfl_xor(sm, 32, 64);

    #pragma unroll
    for (int et = 0; et < 4; ++et) {
        float pr[4], pi[4];
        #pragma unroll
        for (int r = 0; r < 4; ++r) {
            const float w = ex[et][r] * __builtin_amdgcn_rcpf(sm * amp[et][r]);
            pr[r] = w * (aR[et][r] * scale);
            pi[r] = w * (aI[et][r] * scale);
        }
        const int pidx = cq * 64 + ((et * 16 + hi * 4) ^ ((cq & 7) << 3));
        uint2 ur, ui;
        ur.x = cvt2(pr[0], pr[1]); ur.y = cvt2(pr[2], pr[3]);
        ui.x = cvt2(pi[0], pi[1]); ui.y = cvt2(pi[2], pi[3]);
        *(uint2*)&sQr[pidx] = ur;
        *(uint2*)&sQi[pidx] = ui;
    }
    __syncthreads();

    f32x4 xR4[4] = {}, xI4[4] = {};
    #pragma unroll
    for (int ks = 0; ks < 2; ++ks) {
        const int slot = ks * 4 + hi;
        const bfrag pr = rdfrag(sQr, cq, slot);
        const bfrag pi = rdfrag(sQi, cq, slot);
        const bfrag npi = negf(pi);
        #pragma unroll
        for (int dt = 0; dt < 4; ++dt) {
            const int rd = dt * 16 + l15;
            const bfrag vr = *(const bfrag*)&sVr[rd * 72 + ks * 32 + hi * 8];
            const bfrag vi = *(const bfrag*)&sVi[rd * 72 + ks * 32 + hi * 8];
            xR4[dt] = __builtin_amdgcn_mfma_f32_16x16x32_bf16(pr, vr, xR4[dt], 0, 0, 0);
            xR4[dt] = __builtin_amdgcn_mfma_f32_16x16x32_bf16(npi, vi, xR4[dt], 0, 0, 0);
            xI4[dt] = __builtin_amdgcn_mfma_f32_16x16x32_bf16(pi, vr, xI4[dt], 0, 0, 0);
            xI4[dt] = __builtin_amdgcn_mfma_f32_16x16x32_bf16(pr, vi, xI4[dt], 0, 0, 0);
        }
    }

    #pragma unroll
    for (int dt = 0; dt < 4; ++dt) {
        #pragma unroll
        for (int r = 0; r < 4; ++r) {
            const int c = wv * 16 + hi * 4 + r;
            const size_t o = (((size_t)(b * 64 + c) * 256) + t) * 256 + h * 64 + dt * 16 + l15;
            Xr[o] = f2bf(xR4[dt][r]);
            Xi[o] = f2bf(xI4[dt][r]);
        }
    }
}

// ---------------- Stage 3: complex output projection (64x64, W-direct) ----------------
#define O_LOADX(s) { \
    const size_t o_ = (size_t)(m0 + xrow) * 256 + (s) * 32 + xsw * 8; \
    xbr = *(const uint4*)(Xr_g + o_); \
    xbi = *(const uint4*)(Xi_g + o_); }

#define O_WRITE(buf) { \
    unsigned short* B_ = SH + (buf) * 4096; \
    *(uint4*)&B_[xidx] = xbr; \
    *(uint4*)&B_[2048 + xidx] = xbi; }

__global__ __launch_bounds__(256, 5)
void oproj_mfma(const unsigned short* __restrict__ Xr_g, const unsigned short* __restrict__ Xi_g,
                const unsigned short* __restrict__ wimg,
                const float* __restrict__ bo_r, const float* __restrict__ bo_i,
                float* __restrict__ outr, float* __restrict__ outi)
{
    __shared__ __align__(16) unsigned short SH[8192];

    // XCD-chunked bijective swizzle: 4096 blocks = 8 XCDs x 512
    const int bid = blockIdx.x;
    const int work = (bid & 7) * 512 + (bid >> 3);
    const int ny = work & 3;
    const int m0 = (work >> 2) * 64;

    const int tid = threadIdx.x;
    const int lane = tid & 63, wv = tid >> 6;
    const int l15 = lane & 15, hi = lane >> 4;
    const int wm = (wv >> 1) * 32, wn = (wv & 1) * 32;

    const unsigned short* wr_img = wimg + ny * 16384;
    const unsigned short* wi_img = wr_img + 65536;
    const unsigned short* wn_img = wr_img + 131072;

    const int xrow = tid >> 2;
    const int xpos = tid & 3;
    const int xsw = xpos ^ ((xrow >> 1) & 3);
    const int xidx = xrow * 32 + xpos * 8;
    uint4 xbr, xbi;

    const int fb0 = (wn + l15) * 32 + hi * 8;
    const int fb1 = (wn + 16 + l15) * 32 + hi * 8;

    f32x4 accR[2][2] = {}, accI[2][2] = {};

    O_LOADX(0);
    O_WRITE(0);
    __syncthreads();

    #pragma unroll
    for (int s = 0; s < 8; ++s) {
        const bfrag br0 = *(const bfrag*)&wr_img[s * 2048 + fb0];
        const bfrag br1 = *(const bfrag*)&wr_img[s * 2048 + fb1];
        const bfrag bi0 = *(const bfrag*)&wi_img[s * 2048 + fb0];
        const bfrag bi1 = *(const bfrag*)&wi_img[s * 2048 + fb1];
        const bfrag nb0 = *(const bfrag*)&wn_img[s * 2048 + fb0];
        const bfrag nb1 = *(const bfrag*)&wn_img[s * 2048 + fb1];
        if (s < 7) O_LOADX(s + 1);
        const unsigned short* As_r = SH + (s & 1) * 4096;
        const unsigned short* As_i = As_r + 2048;
        bfrag ar[2], ai[2];
        #pragma unroll
        for (int mf = 0; mf < 2; ++mf) {
            const int m = wm + mf * 16 + l15;
            const int idx = m * 32 + ((hi ^ ((m >> 1) & 3)) << 3);
            ar[mf] = *(const bfrag*)&As_r[idx];
            ai[mf] = *(const bfrag*)&As_i[idx];
        }
        #pragma unroll
        for (int mf = 0; mf < 2; ++mf) {
            accR[mf][0] = __builtin_amdgcn_mfma_f32_16x16x32_bf16(ar[mf], br0, accR[mf][0], 0, 0, 0);
            accR[mf][0] = __builtin_amdgcn_mfma_f32_16x16x32_bf16(ai[mf], nb0, accR[mf][0], 0, 0, 0);
            accI[mf][0] = __builtin_amdgcn_mfma_f32_16x16x32_bf16(ai[mf], br0, accI[mf][0], 0, 0, 0);
            accI[mf][0] = __builtin_amdgcn_mfma_f32_16x16x32_bf16(ar[mf], bi0, accI[mf][0], 0, 0, 0);
            accR[mf][1] = __builtin_amdgcn_mfma_f32_16x16x32_bf16(ar[mf], br1, accR[mf][1], 0, 0, 0);
            accR[mf][1] = __builtin_amdgcn_mfma_f32_16x16x32_bf16(ai[mf], nb1, accR[mf][1], 0, 0, 0);
            accI[mf][1] = __builtin_amdgcn_mfma_f32_16x16x32_bf16(ai[mf], br1, accI[mf][1], 0, 0, 0);
            accI[mf][1] = __builtin_amdgcn_mfma_f32_16x16x32_bf16(ar[mf], bi1, accI[mf][1], 0, 0, 0);
        }
        if (s < 7) O_WRITE((s + 1) & 1);
        __syncthreads();
    }

    #pragma unroll
    for (int nf = 0; nf < 2; ++nf) {
        const int n = ny * 64 + wn + nf * 16 + l15;
        const float vbr = bo_r[n], vbi = bo_i[n];
        const float addR = vbr - vbi, addI = vbr + vbi;
        #pragma unroll
        for (int mf = 0; mf < 2; ++mf) {
            #pragma unroll
            for (int r = 0; r < 4; ++r) {
                const size_t o = (size_t)(m0 + wm + mf * 16 + hi * 4 + r) * 256 + n;
                outr[o] = accR[mf][nf][r] + addR;
                outi[o] = accI[mf][nf][r] + addI;
            }
        }
    }
}

extern "C" void kernel_launch(void* const* d_in, const int* in_sizes, int n_in,
                              void* d_out, int out_size, void* d_ws, size_t ws_size,
                              hipStream_t stream)
{
    (void)in_sizes; (void)n_in; (void)out_size; (void)ws_size;
    const float* q_r = (const float*)d_in[0];
    const float* q_i = (const float*)d_in[1];
    const float* k_r = (const float*)d_in[2];
    const float* k_i = (const float*)d_in[3];
    const float* v_r = (const float*)d_in[4];
    const float* v_i = (const float*)d_in[5];
    const int* mask = (const int*)d_in[6];
    const float* wq_r = (const float*)d_in[7];
    const float* wq_i = (const float*)d_in[8];
    const float* bq_r = (const float*)d_in[9];
    const float* bq_i = (const float*)d_in[10];
    const float* wk_r = (const float*)d_in[11];
    const float* wk_i = (const float*)d_in[12];
    const float* bk_r = (const float*)d_in[13];
    const float* bk_i = (const float*)d_in[14];
    const float* wv_r = (const float*)d_in[15];
    const float* wv_i = (const float*)d_in[16];
    const float* bv_r = (const float*)d_in[17];
    const float* bv_i = (const float*)d_in[18];
    const float* wo_r = (const float*)d_in[19];
    const float* wo_i = (const float*)d_in[20];
    const float* bo_r = (const float*)d_in[21];
    const float* bo_i = (const float*)d_in[22];

    const size_t TS = 16777216;
    unsigned short* ws = (unsigned short*)d_ws;
    unsigned short* Q = ws;                      // Qr,Qi,Kr,Ki,Vr,Vi: 6 x TS
    unsigned short* Xr = ws + 6 * TS;
    unsigned short* Xi = ws + 7 * TS;
    unsigned short* wimg_qkv = ws + 6 * TS;      // overlaid on X region (dead until attn)
    unsigned short* wimg_o = ws;                 // overlaid on Q region (dead after attn)

    wprep_kernel<<<dim3(32, 3), 256, 0, stream>>>(wq_r, wq_i, wimg_qkv);
    wprep_kernel<<<dim3(32, 3), 256, 0, stream>>>(wk_r, wk_i, wimg_qkv + 196608);
    wprep_kernel<<<dim3(32, 3), 256, 0, stream>>>(wv_r, wv_i, wimg_qkv + 393216);
    proj_mfma<<<dim3(12288), 256, 0, stream>>>(q_r, q_i, k_r, k_i, v_r, v_i, wimg_qkv,
                                               bq_r, bq_i, bk_r, bk_i, bv_r, bv_i, ws);
    attn_mfma<<<dim3(4096), 256, 0, stream>>>(Q, Q + TS, Q + 2 * TS, Q + 3 * TS,
                                              Q + 4 * TS, Q + 5 * TS, mask, Xr, Xi);
    wprep_kernel<<<dim3(32, 3), 256, 0, stream>>>(wo_r, wo_i, wimg_o);
    oproj_mfma<<<dim3(4096), 256, 0, stream>>>(Xr, Xi, wimg_o, bo_r, bo_i,
                                               (float*)d_out, (float*)d_out + TS);
}

// Round 12
// 334.115 us; speedup vs baseline: 1.2437x; 1.2437x over previous
//
#include <hip/hip_runtime.h>
#include <hip/hip_bf16.h>
#include <cstddef>

#define MIN_VALUE_F (-3.402823466e38f)

// B=4, C=64, T=256, D=256, H=4, DK=64, OUT=256, M = B*C*T = 65536

typedef __attribute__((ext_vector_type(8))) __bf16 bfrag;    // MFMA A/B operand (4 VGPR)
typedef __attribute__((ext_vector_type(4))) float f32x4;     // 16x16 C/D
typedef __attribute__((ext_vector_type(16))) float f32x16;   // 32x32 C/D

__device__ __forceinline__ float bf2f(unsigned int u) {
    union { unsigned int i; float f; } v; v.i = u << 16; return v.f;
}
__device__ __forceinline__ unsigned short f2bf(float f) {
    union { float f; unsigned int i; } v; v.f = f;
    return (unsigned short)((v.i + 0x7fffu + ((v.i >> 16) & 1u)) >> 16);
}
__device__ __forceinline__ unsigned int cvt2(float a, float b) {
    __hip_bfloat16 lo = __float2bfloat16(a);
    __hip_bfloat16 hi = __float2bfloat16(b);
    union { __hip_bfloat16 h[2]; unsigned int u; } x;
    x.h[0] = lo; x.h[1] = hi;
    return x.u;
}
__device__ __forceinline__ bfrag negf(bfrag v) {
    union { bfrag b; unsigned int u[4]; } x; x.b = v;
    #pragma unroll
    for (int i = 0; i < 4; ++i) x.u[i] ^= 0x80008000u;
    return x.b;
}

typedef __attribute__((address_space(3))) void lds_void_t;
typedef const __attribute__((address_space(1))) void gmem_void_t;
__device__ __forceinline__ void glds16(const void* g, void* l) {
    __builtin_amdgcn_global_load_lds((gmem_void_t*)g, (lds_void_t*)l, 16, 0, 0);
}

// fragment read from XOR-swizzled row-major 64x64 bf16 tile (row stride 64 ushorts) [attn]
__device__ __forceinline__ bfrag rdfrag(const unsigned short* arr, int row, int slot) {
    const int s = slot ^ (row & 7);
    return *(const bfrag*)&arr[row * 64 + s * 8];
}

// ---------------- Weight prepass: f32 -> bf16 FRAGMENT-ORDERED images (32x32x16) ----
// Per weight pair: [nt(2)][ri(2)][s(8)][g(4)][h(2)][lane(64)][8ush] = 131072 ush.
// col = nt*128 + g*32 + (lane&31); k = s*32 + h*16 + (lane>>5)*8 + j.
// Staging into LDS is then a pure lane-linear uint4 copy; frag reads are lane-linear.
__global__ __launch_bounds__(256)
void wprep_kernel(const float* __restrict__ wr, const float* __restrict__ wi,
                  unsigned short* __restrict__ dst)
{
    const int cid = blockIdx.x * 256 + threadIdx.x;   // 0..16383
    const int lane = cid & 63;
    const int h  = (cid >> 6) & 1;
    const int g  = (cid >> 7) & 3;
    const int s  = (cid >> 9) & 7;
    const int ri = (cid >> 12) & 1;
    const int nt = cid >> 13;
    const float* w = ri ? wi : wr;
    const int col = nt * 128 + g * 32 + (lane & 31);
    const int kb = s * 32 + h * 16 + (lane >> 5) * 8;
    unsigned int p[4];
    #pragma unroll
    for (int jj = 0; jj < 4; ++jj) {
        const float a = w[(size_t)(kb + 2 * jj) * 256 + col];
        const float b = w[(size_t)(kb + 2 * jj + 1) * 256 + col];
        p[jj] = cvt2(a, b);
    }
    uint4 q; q.x = p[0]; q.y = p[1]; q.z = p[2]; q.w = p[3];
    *(uint4*)&dst[(size_t)cid * 8] = q;
}

// ---------------- Stage 1: complex QKV projection, 32x32x16 MFMA ----------------
// Block 128x128, BK=32, 8 steps, 4 waves (2x2) of 64x64 (2x2 frags of 32x32).
// LDS dbuf 2x32KB, fragment-ordered (lane-linear, conflict-free). One barrier/step.
// Per buf (ush): A_r[0,4096) A_i[4096,8192) W_r[8192,12288) W_i[12288,16384).
#define P_LOADA(s) { \
    const size_t oA_ = (size_t)(m0 + rA) * 256 + (s) * 32 + aq * 8; \
    const size_t oB_ = oA_ + (size_t)64 * 256; \
    fra0 = *(const float4*)(xr + oA_);  fra1 = *(const float4*)(xr + oA_ + 4); \
    frb0 = *(const float4*)(xr + oB_);  frb1 = *(const float4*)(xr + oB_ + 4); \
    fia0 = *(const float4*)(xi + oA_);  fia1 = *(const float4*)(xi + oA_ + 4); \
    fib0 = *(const float4*)(xi + oB_);  fib1 = *(const float4*)(xi + oB_ + 4); }

#define P_LOADW(s) { \
    wbr0 = wru[(s) * 512 + tid];  wbr1 = wru[(s) * 512 + 256 + tid]; \
    wbi0 = wiu[(s) * 512 + tid];  wbi1 = wiu[(s) * 512 + 256 + tid]; }

#define PK4(d_, v0_, v1_) { \
    d_.x = cvt2(v0_.x, v0_.y); d_.y = cvt2(v0_.z, v0_.w); \
    d_.z = cvt2(v1_.x, v1_.y); d_.w = cvt2(v1_.z, v1_.w); }

#define P_WRITE(buf) { \
    unsigned short* B_ = SH + (buf) * 16384; \
    uint4 t_; \
    PK4(t_, fra0, fra1); *(uint4*)&B_[idxA] = t_; \
    PK4(t_, frb0, frb1); *(uint4*)&B_[idxA + 2048] = t_; \
    PK4(t_, fia0, fia1); *(uint4*)&B_[4096 + idxA] = t_; \
    PK4(t_, fib0, fib1); *(uint4*)&B_[4096 + idxA + 2048] = t_; \
    *(uint4*)&B_[8192 + tid * 8] = wbr0; \
    *(uint4*)&B_[8192 + (256 + tid) * 8] = wbr1; \
    *(uint4*)&B_[12288 + tid * 8] = wbi0; \
    *(uint4*)&B_[12288 + (256 + tid) * 8] = wbi1; }

__global__ __launch_bounds__(256, 2)
void proj_mfma(const float* __restrict__ xq_r, const float* __restrict__ xq_i,
               const float* __restrict__ xk_r, const float* __restrict__ xk_i,
               const float* __restrict__ xv_r, const float* __restrict__ xv_i,
               const unsigned short* __restrict__ wimg,
               const float* __restrict__ bq_r, const float* __restrict__ bq_i,
               const float* __restrict__ bk_r, const float* __restrict__ bk_i,
               const float* __restrict__ bv_r, const float* __restrict__ bv_i,
               unsigned short* __restrict__ ws_out)
{
    __shared__ __align__(16) unsigned short SH[32768];   // 64 KB (2 bufs)

    // XCD-chunked bijective swizzle: 3072 blocks = 8 XCDs x 384
    const int bid = blockIdx.x;
    const int work = (bid & 7) * 384 + (bid >> 3);
    const int ny = work & 1;                  // n-tile (2 heads), innermost -> same XCD
    const int m0 = ((work >> 1) & 511) * 128;
    const int pz = work >> 10;

    const float *xr, *xi, *br_, *bi_;
    if (pz == 0)      { xr = xq_r; xi = xq_i; br_ = bq_r; bi_ = bq_i; }
    else if (pz == 1) { xr = xk_r; xi = xk_i; br_ = bk_r; bi_ = bk_i; }
    else              { xr = xv_r; xi = xv_i; br_ = bv_r; bi_ = bv_i; }
    unsigned short* outr = ws_out + (size_t)pz * 2 * 16777216;
    unsigned short* outi = outr + 16777216;

    const int tid = threadIdx.x;
    const int lane = tid & 63, wv = tid >> 6;
    const int l31 = lane & 31, khl = lane >> 5;
    const int wm = (wv >> 1) * 64, wn = (wv & 1) * 64;
    const int wmg = wm >> 5, wng = wn >> 5;

    const unsigned short* wbase = wimg + (size_t)pz * 131072 + ny * 65536;
    const uint4* wru = (const uint4*)wbase;             // [s][512 chunks]
    const uint4* wiu = (const uint4*)(wbase + 32768);

    // A staging: rows rA=tid>>2 (0..63) and rA+64; k-chunk aq = tid&3 (8 f32)
    const int rA = tid >> 2;
    const int aq = tid & 3;
    // fragment-order write slot: g = r>>5, h = aq>>1, lane = (r&31) + (aq&1)*32
    const int idxA = (((rA >> 5) * 2 + (aq >> 1)) * 64 + (rA & 31) + (aq & 1) * 32) * 8;

    float4 fra0, fra1, frb0, frb1, fia0, fia1, fib0, fib1;
    uint4 wbr0, wbr1, wbi0, wbi1;

    f32x16 accR[2][2] = {}, accI[2][2] = {};

    P_LOADA(0); P_LOADW(0);
    P_WRITE(0);
    __syncthreads();

    #pragma unroll
    for (int s = 0; s < 8; ++s) {
        if (s < 7) { P_LOADA(s + 1); P_LOADW(s + 1); }
        const unsigned short* Ab = SH + (s & 1) * 16384;
        #pragma unroll
        for (int h = 0; h < 2; ++h) {
            bfrag ar[2], ai[2], nai[2], br[2], bi[2];
            #pragma unroll
            for (int mf = 0; mf < 2; ++mf) {
                const int off = (((wmg + mf) * 2 + h) * 64 + lane) * 8;
                ar[mf] = *(const bfrag*)&Ab[off];
                ai[mf] = *(const bfrag*)&Ab[4096 + off];
                nai[mf] = negf(ai[mf]);
            }
            #pragma unroll
            for (int nf = 0; nf < 2; ++nf) {
                const int off = (((wng + nf) * 2 + h) * 64 + lane) * 8;
                br[nf] = *(const bfrag*)&Ab[8192 + off];
                bi[nf] = *(const bfrag*)&Ab[12288 + off];
            }
            #pragma unroll
            for (int mf = 0; mf < 2; ++mf) {
                #pragma unroll
                for (int nf = 0; nf < 2; ++nf) {
                    accR[mf][nf] = __builtin_amdgcn_mfma_f32_32x32x16_bf16(ar[mf], br[nf], accR[mf][nf], 0, 0, 0);
                    accR[mf][nf] = __builtin_amdgcn_mfma_f32_32x32x16_bf16(nai[mf], bi[nf], accR[mf][nf], 0, 0, 0);
                    accI[mf][nf] = __builtin_amdgcn_mfma_f32_32x32x16_bf16(ai[mf], br[nf], accI[mf][nf], 0, 0, 0);
                    accI[mf][nf] = __builtin_amdgcn_mfma_f32_32x32x16_bf16(ar[mf], bi[nf], accI[mf][nf], 0, 0, 0);
                }
            }
        }
        if (s < 7) P_WRITE((s + 1) & 1);
        __syncthreads();
    }

    // ---- epilogue: bias, stage 128x128 bf16 tile in LDS (r @0, i @16384), coalesced store
    const int bc = m0 >> 8, b = bc >> 6, c = bc & 63, t0 = m0 & 255;
    #pragma unroll
    for (int nf = 0; nf < 2; ++nf) {
        const int n_loc = wn + nf * 32 + l31;
        const int n_glob = ny * 128 + n_loc;
        const float vbr = br_[n_glob], vbi = bi_[n_glob];
        const float addR = vbr - vbi, addI = vbr + vbi;
        #pragma unroll
        for (int mf = 0; mf < 2; ++mf) {
            #pragma unroll
            for (int reg = 0; reg < 16; ++reg) {
                const int m_loc = wm + mf * 32 + (reg & 3) + 8 * (reg >> 2) + 4 * khl;
                SH[m_loc * 128 + n_loc] = f2bf(accR[mf][nf][reg] + addR);
                SH[16384 + m_loc * 128 + n_loc] = f2bf(accI[mf][nf][reg] + addI);
            }
        }
    }
    __syncthreads();
    const int h0 = ny * 2;
    #pragma unroll
    for (int p = 0; p < 8; ++p) {
        const int L = p * 2048 + tid * 8;
        const int mloc = L >> 7, nloc = L & 127;
        const int hh = nloc >> 6, dk = nloc & 63;
        const size_t g = (((size_t)(b * 4 + h0 + hh) * 256 + (t0 + mloc)) * 64 + c) * 64 + dk;
        *(uint4*)&outr[g] = *(const uint4*)&SH[L];
        *(uint4*)&outi[g] = *(const uint4*)&SH[16384 + L];
    }
}

// ---------------- Stage 2: fused complex attention per (b,h,t), MFMA (unchanged) ------
__global__ __launch_bounds__(256)
void attn_mfma(const unsigned short* __restrict__ Qg_r, const unsigned short* __restrict__ Qg_i,
               const unsigned short* __restrict__ Kg_r, const unsigned short* __restrict__ Kg_i,
               const unsigned short* __restrict__ Vg_r, const unsigned short* __restrict__ Vg_i,
               const int* __restrict__ mask,
               unsigned short* __restrict__ Xr, unsigned short* __restrict__ Xi)
{
    __shared__ __align__(16) unsigned short sQr[4096], sQi[4096];   // Q, then P
    __shared__ __align__(16) unsigned short sKr[4096], sKi[4096];
    __shared__ __align__(16) unsigned short sVr[4608], sVi[4608];   // V^T, rows padded to 72
    __shared__ int smask[64];

    const int bht = blockIdx.x;
    const int b = bht >> 10;
    const int h = (bht >> 8) & 3;
    const int t = bht & 255;
    const size_t base = (size_t)bht * 4096;
    const int tid = threadIdx.x;
    const int lane = tid & 63, wv = tid >> 6;
    const int l15 = lane & 15, hi = lane >> 4;

    const int ep = (lane & 31) * 2;
    const int dch = wv * 2 + (lane >> 5);
    const unsigned short* vr0p = Vg_r + base + (size_t)ep * 64 + dch * 8;
    const unsigned short* vi0p = Vg_i + base + (size_t)ep * 64 + dch * 8;
    const uint4 vr0 = *(const uint4*)vr0p;
    const uint4 vr1 = *(const uint4*)(vr0p + 64);
    const uint4 vi0 = *(const uint4*)vi0p;
    const uint4 vi1 = *(const uint4*)(vi0p + 64);

    #pragma unroll
    for (int i = 0; i < 2; ++i) {
        const int ch = wv * 128 + i * 64 + lane;
        const int r = ch >> 3, cg = ch & 7;
        const int so = r * 64 + ((cg ^ (r & 7)) << 3);
        const int dofs = (wv * 128 + i * 64) << 3;
        glds16(Qg_r + base + so, &sQr[dofs]);
        glds16(Qg_i + base + so, &sQi[dofs]);
        glds16(Kg_r + base + so, &sKr[dofs]);
        glds16(Kg_i + base + so, &sKi[dofs]);
    }
    if (tid < 64) smask[tid] = mask[b * 64 + tid];

    {
        union { uint4 v; unsigned short s[8]; } ar0, ar1, ai0, ai1;
        ar0.v = vr0; ar1.v = vr1; ai0.v = vi0; ai1.v = vi1;
        #pragma unroll
        for (int j = 0; j < 8; ++j) {
            const int d = dch * 8 + j;
            *(unsigned int*)&sVr[d * 72 + ep] = (unsigned)ar0.s[j] | ((unsigned)ar1.s[j] << 16);
            *(unsigned int*)&sVi[d * 72 + ep] = (unsigned)ai0.s[j] | ((unsigned)ai1.s[j] << 16);
        }
    }
    __syncthreads();

    const int cq = wv * 16 + l15;
    f32x4 aR[4] = {}, aI[4] = {};
    #pragma unroll
    for (int ks = 0; ks < 2; ++ks) {
        const int slot = ks * 4 + hi;
        const bfrag qr = rdfrag(sQr, cq, slot);
        const bfrag qi = rdfrag(sQi, cq, slot);
        const bfrag nqi = negf(qi);
        #pragma unroll
        for (int et = 0; et < 4; ++et) {
            const int re = et * 16 + l15;
            const bfrag kr = rdfrag(sKr, re, slot);
            const bfrag ki = rdfrag(sKi, re, slot);
            aR[et] = __builtin_amdgcn_mfma_f32_16x16x32_bf16(kr, qr, aR[et], 0, 0, 0);
            aR[et] = __builtin_amdgcn_mfma_f32_16x16x32_bf16(ki, qi, aR[et], 0, 0, 0);
            aI[et] = __builtin_amdgcn_mfma_f32_16x16x32_bf16(ki, qr, aI[et], 0, 0, 0);
            aI[et] = __builtin_amdgcn_mfma_f32_16x16x32_bf16(kr, nqi, aI[et], 0, 0, 0);
        }
    }
    __syncthreads();

    const float scale = 0.125f;
    float amp[4][4], ex[4][4];
    float mx = MIN_VALUE_F;
    #pragma unroll
    for (int et = 0; et < 4; ++et) {
        #pragma unroll
        for (int r = 0; r < 4; ++r) {
            const float sr = aR[et][r] * scale;
            const float si = aI[et][r] * scale;
            float a = sqrtf(fmaf(sr, sr, si * si));
            if (smask[et * 16 + hi * 4 + r] == 0) a = MIN_VALUE_F;
            amp[et][r] = a;
            mx = fmaxf(mx, a);
        }
    }
    mx = fmaxf(mx, __shfl_xor(mx, 16, 64));
    mx = fmaxf(mx, __shfl_xor(mx, 32, 64));
    float sm = 0.f;
    #pragma unroll
    for (int et = 0; et < 4; ++et) {
        #pragma unroll
        for (int r = 0; r < 4; ++r) {
            const float e_ = expf(amp[et][r] - mx);
            ex[et][r] = e_; sm += e_;
        }
    }
    sm += __shfl_xor(sm, 16, 64);
    sm += __shfl_xor(sm, 32, 64);

    #pragma unroll
    for (int et = 0; et < 4; ++et) {
        float pr[4], pi[4];
        #pragma unroll
        for (int r = 0; r < 4; ++r) {
            const float w = ex[et][r] * __builtin_amdgcn_rcpf(sm * amp[et][r]);
            pr[r] = w * (aR[et][r] * scale);
            pi[r] = w * (aI[et][r] * scale);
        }
        const int pidx = cq * 64 + ((et * 16 + hi * 4) ^ ((cq & 7) << 3));
        uint2 ur, ui;
        ur.x = cvt2(pr[0], pr[1]); ur.y = cvt2(pr[2], pr[3]);
        ui.x = cvt2(pi[0], pi[1]); ui.y = cvt2(pi[2], pi[3]);
        *(uint2*)&sQr[pidx] = ur;
        *(uint2*)&sQi[pidx] = ui;
    }
    __syncthreads();

    f32x4 xR4[4] = {}, xI4[4] = {};
    #pragma unroll
    for (int ks = 0; ks < 2; ++ks) {
        const int slot = ks * 4 + hi;
        const bfrag pr = rdfrag(sQr, cq, slot);
        const bfrag pi = rdfrag(sQi, cq, slot);
        const bfrag npi = negf(pi);
        #pragma unroll
        for (int dt = 0; dt < 4; ++dt) {
            const int rd = dt * 16 + l15;
            const bfrag vr = *(const bfrag*)&sVr[rd * 72 + ks * 32 + hi * 8];
            const bfrag vi = *(const bfrag*)&sVi[rd * 72 + ks * 32 + hi * 8];
            xR4[dt] = __builtin_amdgcn_mfma_f32_16x16x32_bf16(pr, vr, xR4[dt], 0, 0, 0);
            xR4[dt] = __builtin_amdgcn_mfma_f32_16x16x32_bf16(npi, vi, xR4[dt], 0, 0, 0);
            xI4[dt] = __builtin_amdgcn_mfma_f32_16x16x32_bf16(pi, vr, xI4[dt], 0, 0, 0);
            xI4[dt] = __builtin_amdgcn_mfma_f32_16x16x32_bf16(pr, vi, xI4[dt], 0, 0, 0);
        }
    }

    #pragma unroll
    for (int dt = 0; dt < 4; ++dt) {
        #pragma unroll
        for (int r = 0; r < 4; ++r) {
            const int c = wv * 16 + hi * 4 + r;
            const size_t o = (((size_t)(b * 64 + c) * 256) + t) * 256 + h * 64 + dt * 16 + l15;
            Xr[o] = f2bf(xR4[dt][r]);
            Xi[o] = f2bf(xI4[dt][r]);
        }
    }
}

// ---------------- Stage 3: complex output projection, 32x32x16 MFMA ----------------
#define O_LOADX(s) { \
    const size_t oA_ = (size_t)(m0 + rA) * 256 + (s) * 32 + aq * 8; \
    const size_t oB_ = oA_ + (size_t)64 * 256; \
    xra = *(const uint4*)(Xr_g + oA_);  xrb = *(const uint4*)(Xr_g + oB_); \
    xia = *(const uint4*)(Xi_g + oA_);  xib = *(const uint4*)(Xi_g + oB_); }

#define O_LOADW(s) { \
    wbr0 = wru[(s) * 512 + tid];  wbr1 = wru[(s) * 512 + 256 + tid]; \
    wbi0 = wiu[(s) * 512 + tid];  wbi1 = wiu[(s) * 512 + 256 + tid]; }

#define O_WRITE(buf) { \
    unsigned short* B_ = SH + (buf) * 16384; \
    *(uint4*)&B_[idxA] = xra; \
    *(uint4*)&B_[idxA + 2048] = xrb; \
    *(uint4*)&B_[4096 + idxA] = xia; \
    *(uint4*)&B_[4096 + idxA + 2048] = xib; \
    *(uint4*)&B_[8192 + tid * 8] = wbr0; \
    *(uint4*)&B_[8192 + (256 + tid) * 8] = wbr1; \
    *(uint4*)&B_[12288 + tid * 8] = wbi0; \
    *(uint4*)&B_[12288 + (256 + tid) * 8] = wbi1; }

__global__ __launch_bounds__(256, 2)
void oproj_mfma(const unsigned short* __restrict__ Xr_g, const unsigned short* __restrict__ Xi_g,
                const unsigned short* __restrict__ wimg,
                const float* __restrict__ bo_r, const float* __restrict__ bo_i,
                float* __restrict__ outr, float* __restrict__ outi)
{
    __shared__ __align__(16) unsigned short SH[32768];

    // XCD-chunked bijective swizzle: 1024 blocks = 8 XCDs x 128
    const int bid = blockIdx.x;
    const int work = (bid & 7) * 128 + (bid >> 3);
    const int ny = work & 1;
    const int m0 = (work >> 1) * 128;

    const int tid = threadIdx.x;
    const int lane = tid & 63, wv = tid >> 6;
    const int l31 = lane & 31, khl = lane >> 5;
    const int wm = (wv >> 1) * 64, wn = (wv & 1) * 64;
    const int wmg = wm >> 5, wng = wn >> 5;

    const unsigned short* wbase = wimg + ny * 65536;
    const uint4* wru = (const uint4*)wbase;
    const uint4* wiu = (const uint4*)(wbase + 32768);

    const int rA = tid >> 2;
    const int aq = tid & 3;
    const int idxA = (((rA >> 5) * 2 + (aq >> 1)) * 64 + (rA & 31) + (aq & 1) * 32) * 8;

    uint4 xra, xrb, xia, xib, wbr0, wbr1, wbi0, wbi1;

    f32x16 accR[2][2] = {}, accI[2][2] = {};

    O_LOADX(0); O_LOADW(0);
    O_WRITE(0);
    __syncthreads();

    #pragma unroll
    for (int s = 0; s < 8; ++s) {
        if (s < 7) { O_LOADX(s + 1); O_LOADW(s + 1); }
        const unsigned short* Ab = SH + (s & 1) * 16384;
        #pragma unroll
        for (int h = 0; h < 2; ++h) {
            bfrag ar[2], ai[2], nai[2], br[2], bi[2];
            #pragma unroll
            for (int mf = 0; mf < 2; ++mf) {
                const int off = (((wmg + mf) * 2 + h) * 64 + lane) * 8;
                ar[mf] = *(const bfrag*)&Ab[off];
                ai[mf] = *(const bfrag*)&Ab[4096 + off];
                nai[mf] = negf(ai[mf]);
            }
            #pragma unroll
            for (int nf = 0; nf < 2; ++nf) {
                const int off = (((wng + nf) * 2 + h) * 64 + lane) * 8;
                br[nf] = *(const bfrag*)&Ab[8192 + off];
                bi[nf] = *(const bfrag*)&Ab[12288 + off];
            }
            #pragma unroll
            for (int mf = 0; mf < 2; ++mf) {
                #pragma unroll
                for (int nf = 0; nf < 2; ++nf) {
                    accR[mf][nf] = __builtin_amdgcn_mfma_f32_32x32x16_bf16(ar[mf], br[nf], accR[mf][nf], 0, 0, 0);
                    accR[mf][nf] = __builtin_amdgcn_mfma_f32_32x32x16_bf16(nai[mf], bi[nf], accR[mf][nf], 0, 0, 0);
                    accI[mf][nf] = __builtin_amdgcn_mfma_f32_32x32x16_bf16(ai[mf], br[nf], accI[mf][nf], 0, 0, 0);
                    accI[mf][nf] = __builtin_amdgcn_mfma_f32_32x32x16_bf16(ar[mf], bi[nf], accI[mf][nf], 0, 0, 0);
                }
            }
        }
        if (s < 7) O_WRITE((s + 1) & 1);
        __syncthreads();
    }

    #pragma unroll
    for (int nf = 0; nf < 2; ++nf) {
        const int n = ny * 128 + wn + nf * 32 + l31;
        const float vbr = bo_r[n], vbi = bo_i[n];
        const float addR = vbr - vbi, addI = vbr + vbi;
        #pragma unroll
        for (int mf = 0; mf < 2; ++mf) {
            #pragma unroll
            for (int reg = 0; reg < 16; ++reg) {
                const int m = m0 + wm + mf * 32 + (reg & 3) + 8 * (reg >> 2) + 4 * khl;
                outr[(size_t)m * 256 + n] = accR[mf][nf][reg] + addR;
                outi[(size_t)m * 256 + n] = accI[mf][nf][reg] + addI;
            }
        }
    }
}

extern "C" void kernel_launch(void* const* d_in, const int* in_sizes, int n_in,
                              void* d_out, int out_size, void* d_ws, size_t ws_size,
                              hipStream_t stream)
{
    (void)in_sizes; (void)n_in; (void)out_size; (void)ws_size;
    const float* q_r = (const float*)d_in[0];
    const float* q_i = (const float*)d_in[1];
    const float* k_r = (const float*)d_in[2];
    const float* k_i = (const float*)d_in[3];
    const float* v_r = (const float*)d_in[4];
    const float* v_i = (const float*)d_in[5];
    const int* mask = (const int*)d_in[6];
    const float* wq_r = (const float*)d_in[7];
    const float* wq_i = (const float*)d_in[8];
    const float* bq_r = (const float*)d_in[9];
    const float* bq_i = (const float*)d_in[10];
    const float* wk_r = (const float*)d_in[11];
    const float* wk_i = (const float*)d_in[12];
    const float* bk_r = (const float*)d_in[13];
    const float* bk_i = (const float*)d_in[14];
    const float* wv_r = (const float*)d_in[15];
    const float* wv_i = (const float*)d_in[16];
    const float* bv_r = (const float*)d_in[17];
    const float* bv_i = (const float*)d_in[18];
    const float* wo_r = (const float*)d_in[19];
    const float* wo_i = (const float*)d_in[20];
    const float* bo_r = (const float*)d_in[21];
    const float* bo_i = (const float*)d_in[22];

    const size_t TS = 16777216;
    unsigned short* ws = (unsigned short*)d_ws;
    unsigned short* Q = ws;                      // Qr,Qi,Kr,Ki,Vr,Vi: 6 x TS
    unsigned short* Xr = ws + 6 * TS;
    unsigned short* Xi = ws + 7 * TS;
    unsigned short* wimg_qkv = ws + 6 * TS;      // overlaid on X region (dead until attn)
    unsigned short* wimg_o = ws;                 // overlaid on Q region (dead after attn)

    wprep_kernel<<<dim3(64), 256, 0, stream>>>(wq_r, wq_i, wimg_qkv);
    wprep_kernel<<<dim3(64), 256, 0, stream>>>(wk_r, wk_i, wimg_qkv + 131072);
    wprep_kernel<<<dim3(64), 256, 0, stream>>>(wv_r, wv_i, wimg_qkv + 262144);
    proj_mfma<<<dim3(3072), 256, 0, stream>>>(q_r, q_i, k_r, k_i, v_r, v_i, wimg_qkv,
                                              bq_r, bq_i, bk_r, bk_i, bv_r, bv_i, ws);
    attn_mfma<<<dim3(4096), 256, 0, stream>>>(Q, Q + TS, Q + 2 * TS, Q + 3 * TS,
                                              Q + 4 * TS, Q + 5 * TS, mask, Xr, Xi);
    wprep_kernel<<<dim3(64), 256, 0, stream>>>(wo_r, wo_i, wimg_o);
    oproj_mfma<<<dim3(1024), 256, 0, stream>>>(Xr, Xi, wimg_o, bo_r, bo_i,
                                               (float*)d_out, (float*)d_out + TS);
}